// Round 1
// baseline (362.535 us; speedup 1.0000x reference)
//
#include <hip/hip_runtime.h>

// LocallyConnected2D: out[b,f,or,oc] = relu( sum_{c,kh,kw} x[b,c,2or+kh,2oc+kw]*W[f,c,2or+kh,2oc+kw] + bias )
// bias raw-reshaped: bias_flat[f*OR*OC + or*OC + oc]
//
// Shapes: B=32 C=32 H=128 W=128 F=64 OR=OC=64. Memory-bound (~236 MB min traffic).
// Block = (or, 4-oc tile), covers ALL b and ALL f so x and W are each read from
// HBM exactly once. 256 threads, 32 f32 accumulators/thread (4b x 4f x 2oc).

#define BB  32
#define CC  32
#define HH  128
#define WWD 128
#define FF  64
#define ORR 64
#define OCC 64
#define CB  4   // channels staged per K-iteration

__global__ __launch_bounds__(256, 4) void lc2d_kernel(
    const float* __restrict__ x, const float* __restrict__ wgt,
    const float* __restrict__ bias, float* __restrict__ out)
{
    // LDS: [row = ci*16 + kh*8 + w][lane-dim], XOR-swizzled quads so that
    // compute ds_read_b128 is conflict-free and staging writes are <=2-way.
    __shared__ float Xs[CB * 16 * 32];  // 8 KB
    __shared__ float Ws[CB * 16 * 64];  // 16 KB

    const int tid    = threadIdx.x;
    const int octile = blockIdx.x;   // 0..15 -> oc0 = octile*4
    const int orr    = blockIdx.y;   // 0..63
    const int w0     = octile * 8;   // 8 w columns per block (4 oc * KC)
    const int h0     = orr * 2;

    const int bg     = tid & 7;         // b-group (x4)  -> b = bg*4 + i
    const int fg     = (tid >> 3) & 15; // f-group (x4)  -> f = fg*4 + q
    const int ochalf = tid >> 7;        // 0..1 -> thread's ocs = octile*4 + ochalf*2 + {0,1}

    float acc[2][4][4];
#pragma unroll
    for (int j = 0; j < 2; ++j)
#pragma unroll
        for (int i = 0; i < 4; ++i)
#pragma unroll
            for (int q = 0; q < 4; ++q) acc[j][i][q] = 0.f;

    for (int it = 0; it < CC / CB; ++it) {
        const int c0 = it * CB;
        __syncthreads();

        // ---- stage x slice: x[0..31][c0..c0+3][h0..h0+1][w0..w0+7] = 512 float4
#pragma unroll
        for (int k = 0; k < 2; ++k) {
            const int idx  = tid + k * 256;
            const int half = idx & 1;        // which float4 of the 8-float row
            const int row  = idx >> 1;       // b*8 + ci*2 + kh
            const int kh   = row & 1;
            const int ci   = (row >> 1) & 3;
            const int b    = row >> 3;
            const float4 v = *(const float4*)(x +
                (((b * CC + c0 + ci) * HH + h0 + kh) * WWD + w0 + half * 4));
            const int lrow = ci * 16 + kh * 8 + half * 4;   // multiple of 4
            const int s    = (lrow >> 2) & 7;
            const int base = (((b >> 2) ^ s) << 2) + (b & 3);
            Xs[(lrow + 0) * 32 + base] = v.x;
            Xs[(lrow + 1) * 32 + base] = v.y;
            Xs[(lrow + 2) * 32 + base] = v.z;
            Xs[(lrow + 3) * 32 + base] = v.w;
        }

        // ---- stage W slice: W[0..63][c0..c0+3][h0..h0+1][w0..w0+7] = 1024 float4
#pragma unroll
        for (int k = 0; k < 4; ++k) {
            const int idx  = tid + k * 256;
            const int half = idx & 1;
            const int row  = idx >> 1;       // f*8 + ci*2 + kh
            const int kh   = row & 1;
            const int ci   = (row >> 1) & 3;
            const int f    = row >> 3;
            const float4 v = *(const float4*)(wgt +
                (((f * CC + c0 + ci) * HH + h0 + kh) * WWD + w0 + half * 4));
            const int lrow = ci * 16 + kh * 8 + half * 4;
            const int s    = (lrow >> 2) & 7;
            const int fq   = f >> 2;
            const int base = (((fq & 8) | ((fq ^ s) & 7)) << 2) + (f & 3);
            Ws[(lrow + 0) * 64 + base] = v.x;
            Ws[(lrow + 1) * 64 + base] = v.y;
            Ws[(lrow + 2) * 64 + base] = v.z;
            Ws[(lrow + 3) * 64 + base] = v.w;
        }
        __syncthreads();

        // ---- compute: per (ci,kh,oc,kw): 2x ds_read_b128 + 16 FMA
#pragma unroll
        for (int ci = 0; ci < CB; ++ci)
#pragma unroll
        for (int kh = 0; kh < 2; ++kh)
#pragma unroll
        for (int j = 0; j < 2; ++j)
#pragma unroll
        for (int kw = 0; kw < 2; ++kw) {
            const int wloc = kh * 8 + (ochalf * 2 + j) * 2 + kw;
            const int row  = ci * 16 + wloc;
            const int s    = (row >> 2) & 7;
            const float4 xv = *(const float4*)&Xs[row * 32 + ((bg ^ s) << 2)];
            const float4 wv = *(const float4*)&Ws[row * 64 + (((fg & 8) | ((fg ^ s) & 7)) << 2)];
            const float xa[4] = {xv.x, xv.y, xv.z, xv.w};
            const float wa[4] = {wv.x, wv.y, wv.z, wv.w};
#pragma unroll
            for (int i = 0; i < 4; ++i)
#pragma unroll
                for (int q = 0; q < 4; ++q)
                    acc[j][i][q] = fmaf(xa[i], wa[q], acc[j][i][q]);
        }
    }

    // ---- epilogue: bias (raw reshape) + relu, float2 stores (oc pair)
    const int oc0 = octile * 4 + ochalf * 2;
#pragma unroll
    for (int i = 0; i < 4; ++i) {
        const int b = bg * 4 + i;
#pragma unroll
        for (int q = 0; q < 4; ++q) {
            const int f = fg * 4 + q;
            const float2 bv = *(const float2*)(bias + f * (ORR * OCC) + orr * OCC + oc0);
            float2 o;
            o.x = fmaxf(acc[0][i][q] + bv.x, 0.f);
            o.y = fmaxf(acc[1][i][q] + bv.y, 0.f);
            *(float2*)(out + ((b * FF + f) * ORR + orr) * OCC + oc0) = o;
        }
    }
}

extern "C" void kernel_launch(void* const* d_in, const int* in_sizes, int n_in,
                              void* d_out, int out_size, void* d_ws, size_t ws_size,
                              hipStream_t stream) {
    (void)in_sizes; (void)n_in; (void)d_ws; (void)ws_size; (void)out_size;
    const float* x    = (const float*)d_in[0];
    const float* wgt  = (const float*)d_in[1];
    const float* bias = (const float*)d_in[2];
    float* out        = (float*)d_out;
    dim3 grid(OCC / 4, ORR, 1);   // 16 x 64 = 1024 blocks
    lc2d_kernel<<<grid, dim3(256, 1, 1), 0, stream>>>(x, wgt, bias, out);
}

// Round 2
// 332.797 us; speedup vs baseline: 1.0894x; 1.0894x over previous
//
#include <hip/hip_runtime.h>

// LocallyConnected2D: out[b,f,or,oc] = relu( sum_{c,kh,kw} x[b,c,2or+kh,2oc+kw]*W[f,c,2or+kh,2oc+kw] + bias )
// bias raw-reshaped: bias_flat[f*OR*OC + or*OC + oc]
//
// B=32 C=32 H=128 W=128 F=64 OR=OC=64. Memory-bound: ideal traffic ~236 MB -> ~37 us.
// Block = (orr, 8-oc tile) => w-footprint 16 floats = 64 B (full sector, no fetch split).
// Block covers ALL b and ALL f so x/W are read from HBM exactly once.
// Grid 512 blocks x 512 threads = 2 blocks/CU (16 waves) -> barrier overlap across blocks.
// Register-prefetch pipeline: load chunk k+1 into regs while computing chunk k from LDS.
// XCD pairing: oc-adjacent blocks (sharing 64-B output sectors) get ids differing by 256
// (same id%8 -> same XCD) so L2 merges their 32-B write halves.

#define BB  32
#define CC  32
#define HH  128
#define WWD 128
#define FF  64
#define ORR 64
#define OCC 64
#define CB  4           // channels staged per K-iteration
#define NIT (CC / CB)   // 8

__global__ __launch_bounds__(512, 4) void lc2d_kernel(
    const float* __restrict__ x, const float* __restrict__ wgt,
    const float* __restrict__ bias, float* __restrict__ out)
{
    // LDS: [row = ci*2+kh (8)][w (16)][col (b or f), XOR-swizzled]
    // col = ((hi ^ (w>>2) ^ (kh<<2)) & 7 [| hi&8]) * 4 + ((lo & 3) ^ ci)
    // -> stage writes ~2-way (free), compute ds_read_b128 at bank floor.
    __shared__ __align__(16) float Xs[8 * 16 * 32];  // 16 KB
    __shared__ __align__(16) float Ws[8 * 16 * 64];  // 32 KB

    const int tid = threadIdx.x;
    const int id  = blockIdx.x;
    // XCD-pair swizzle: oct = ((id&255)&3)*2 + (id>>8); orr = (id&255)>>2
    const int ophase = id >> 8;        // 0..1
    const int rem    = id & 255;
    const int orr    = rem >> 2;       // 0..63
    const int oct    = ((rem & 3) << 1) | ophase;  // 0..7
    const int w0     = oct * 16;
    const int h0     = orr * 2;

    const int ocg = tid & 3;           // oc pair: oc = oct*8 + ocg*2 + j
    const int bg  = (tid >> 2) & 7;    // b = bg*4 + i
    const int fg  = tid >> 5;          // f = fg*4 + q   (0..15)

    // ---- staging decode (idx = tid + r*512 = {b|f}*32 + ci*8 + kh*4 + wq)
    const float* xp[2];
    int xs_off[2];
#pragma unroll
    for (int r = 0; r < 2; ++r) {
        const int idx = tid + r * 512;
        const int wq = idx & 3, kh = (idx >> 2) & 1, ci = (idx >> 3) & 3, b = idx >> 5;
        xp[r] = x + (((b * CC + ci) * HH + h0 + kh) * WWD + w0 + wq * 4);
        const int s  = wq ^ (kh << 2);
        const int cg = ((b >> 2) ^ s) & 7;
        xs_off[r] = ((ci * 2 + kh) * 16 + wq * 4) * 32 + cg * 4 + ((b & 3) ^ ci);
    }
    const float* wp[4];
    int ws_off[4];
#pragma unroll
    for (int r = 0; r < 4; ++r) {
        const int idx = tid + r * 512;
        const int wq = idx & 3, kh = (idx >> 2) & 1, ci = (idx >> 3) & 3, f = idx >> 5;
        wp[r] = wgt + (((f * CC + ci) * HH + h0 + kh) * WWD + w0 + wq * 4);
        const int s  = wq ^ (kh << 2);
        const int cg = (((f >> 2) ^ s) & 7) | ((f >> 2) & 8);
        ws_off[r] = ((ci * 2 + kh) * 16 + wq * 4) * 64 + cg * 4 + ((f & 3) ^ ci);
    }

    // prefetch chunk 0
    float4 rx[2], rw[4];
#pragma unroll
    for (int r = 0; r < 2; ++r) rx[r] = *(const float4*)xp[r];
#pragma unroll
    for (int r = 0; r < 4; ++r) rw[r] = *(const float4*)wp[r];

    float acc[2][4][4];
#pragma unroll
    for (int j = 0; j < 2; ++j)
#pragma unroll
        for (int i = 0; i < 4; ++i)
#pragma unroll
            for (int q = 0; q < 4; ++q) acc[j][i][q] = 0.f;

    for (int it = 0; it < NIT; ++it) {
        __syncthreads();  // previous compute done -> LDS free
        // regs -> LDS (implicit vmcnt wait on the prefetch here)
#pragma unroll
        for (int r = 0; r < 2; ++r) {
            Xs[xs_off[r] +  0] = rx[r].x;
            Xs[xs_off[r] + 32] = rx[r].y;
            Xs[xs_off[r] + 64] = rx[r].z;
            Xs[xs_off[r] + 96] = rx[r].w;
        }
#pragma unroll
        for (int r = 0; r < 4; ++r) {
            Ws[ws_off[r] +   0] = rw[r].x;
            Ws[ws_off[r] +  64] = rw[r].y;
            Ws[ws_off[r] + 128] = rw[r].z;
            Ws[ws_off[r] + 192] = rw[r].w;
        }
        __syncthreads();
        // issue next chunk's loads before compute (overlap HBM with VALU)
        if (it + 1 < NIT) {
#pragma unroll
            for (int r = 0; r < 2; ++r) { xp[r] += CB * HH * WWD; rx[r] = *(const float4*)xp[r]; }
#pragma unroll
            for (int r = 0; r < 4; ++r) { wp[r] += CB * HH * WWD; rw[r] = *(const float4*)wp[r]; }
        }
        // compute chunk it from LDS
#pragma unroll
        for (int ci = 0; ci < CB; ++ci)
#pragma unroll
        for (int kh = 0; kh < 2; ++kh) {
            const int row = ci * 2 + kh;
#pragma unroll
            for (int j = 0; j < 2; ++j)
#pragma unroll
            for (int kw = 0; kw < 2; ++kw) {
                const int w = ocg * 4 + j * 2 + kw;
                const int s = (w >> 2) ^ (kh << 2);
                const float4 xv = *(const float4*)&Xs[(row * 16 + w) * 32 + (((bg ^ s) & 7) << 2)];
                const float4 wv = *(const float4*)&Ws[(row * 16 + w) * 64 + ((((fg ^ s) & 7) | (fg & 8)) << 2)];
                const float xa[4] = {xv.x, xv.y, xv.z, xv.w};
                const float wa[4] = {wv.x, wv.y, wv.z, wv.w};
#pragma unroll
                for (int i = 0; i < 4; ++i)
#pragma unroll
                    for (int q = 0; q < 4; ++q)
                        acc[j][i][q] = fmaf(xa[i ^ ci], wa[q ^ ci], acc[j][i][q]);
            }
        }
    }

    // ---- epilogue: bias (raw reshape) + relu; 4-lane x 8 B = 32 B segments,
    // partner block (same XCD) writes the adjacent 32 B of each 64-B sector.
    const int oc0 = oct * 8 + ocg * 2;
#pragma unroll
    for (int q = 0; q < 4; ++q) {
        const int f = fg * 4 + q;
        const float2 bv = *(const float2*)(bias + f * (ORR * OCC) + orr * OCC + oc0);
#pragma unroll
        for (int i = 0; i < 4; ++i) {
            const int b = bg * 4 + i;
            float2 o;
            o.x = fmaxf(acc[0][i][q] + bv.x, 0.f);
            o.y = fmaxf(acc[1][i][q] + bv.y, 0.f);
            *(float2*)(out + ((b * FF + f) * ORR + orr) * OCC + oc0) = o;
        }
    }
}

extern "C" void kernel_launch(void* const* d_in, const int* in_sizes, int n_in,
                              void* d_out, int out_size, void* d_ws, size_t ws_size,
                              hipStream_t stream) {
    (void)in_sizes; (void)n_in; (void)d_ws; (void)ws_size; (void)out_size;
    const float* x    = (const float*)d_in[0];
    const float* wgt  = (const float*)d_in[1];
    const float* bias = (const float*)d_in[2];
    float* out        = (float*)d_out;
    lc2d_kernel<<<dim3(512, 1, 1), dim3(512, 1, 1), 0, stream>>>(x, wgt, bias, out);
}